// Round 5
// baseline (323.948 us; speedup 1.0000x reference)
//
#include <hip/hip_runtime.h>
#include <math.h>

// PhysQuadModel: batched RK4 rollout of quadrotor dynamics.
// One thread per trajectory (B=8192), 256 sequential RK4 steps.
// R2: quaternion carried as loop state (exp(log(q))==q), poly atan2 for the
//     output-only log map, reciprocal-multiplies, v_rsq normalize.
// R3: distance-2 u prefetch (268->227us rocprof; under-predicted).
// R4: depth-8 u prefetch pipeline (8 outstanding loads, issued 8 bodies
//     ahead -> HBM latency fully hidden, MLP=8) + nontemporal output stores.
//     R4b: nontemporal builtin needs a clang ext_vector_type, not HIP float4.

namespace {
constexpr int   kB    = 8192;
constexpr int   kN    = 256;
constexpr float kDT   = 0.01f;
constexpr float kMG   = 0.033f * 9.81f;        // M*G
constexpr float kTmax = 1.9f * 0.033f * 9.81f; // 0.6150870
constexpr float kKT   = 3.8e-08f;
constexpr float kKC   = 3.8e-11f;
constexpr float kArm  = 0.04f;
constexpr float kInvM = 1.0f / 0.033f;
constexpr float kJx   = 1.4e-05f, kJy = 1.4e-05f, kJz = 2.17e-05f;
constexpr float kInvJx = 1.0f / 1.4e-05f, kInvJy = 1.0f / 1.4e-05f,
                kInvJz = 1.0f / 2.17e-05f;
constexpr float kTq0  = 0.009f, kTq1 = 0.009f, kTq2 = 0.002f;
constexpr float kH    = 0.005f;                // 0.5*dt
constexpr float kDT6  = 0.0016666667f;         // dt/6
constexpr int   kPF   = 8;                     // prefetch pipeline depth
}

typedef float f32x4 __attribute__((ext_vector_type(4)));  // clang vector for NT stores

__device__ __forceinline__ float fast_rcp(float x) { return __builtin_amdgcn_rcpf(x); }
__device__ __forceinline__ float fast_rsq(float x) { return __builtin_amdgcn_rsqf(x); }

// atan2 for y >= 0, result in [0, pi]. Minimax atan poly on [0,1], err ~1e-5.
__device__ __forceinline__ float atan2_pos(float y, float x) {
  float axx = fabsf(x);
  float mn  = fminf(y, axx);
  float mx  = fmaxf(y, axx);
  float t   = mn * fast_rcp(mx);
  float t2  = t * t;
  float p = fmaf(t2, -0.01172120f, 0.05265332f);
  p = fmaf(t2, p, -0.11643287f);
  p = fmaf(t2, p, 0.19354346f);
  p = fmaf(t2, p, -0.33262347f);
  p = fmaf(t2, p, 0.99997726f);
  p *= t;
  p = (y > axx) ? (1.5707963268f - p) : p;
  p = (x < 0.0f) ? (3.1415926536f - p) : p;
  return p;
}

// accurate version used ONCE at init (outside the hot loop)
__device__ __forceinline__ void so3_to_quat_init(float rx, float ry, float rz,
                                                 float& qx, float& qy, float& qz, float& qw) {
  float theta = sqrtf(rx * rx + ry * ry + rz * rz);
  float half  = 0.5f * theta;
  float s     = sinf(half);
  float c     = cosf(half);
  float k     = s / (theta + 1e-8f);
  bool  small = theta < 1e-6f;
  k  = small ? 0.5f : k;
  qw = small ? 1.0f : c;
  qx = k * rx; qy = k * ry; qz = k * rz;
}

// log map, output-only path (not fed back into state)
__device__ __forceinline__ void quat_to_so3_fast(float qx, float qy, float qz, float qw,
                                                 float& rx, float& ry, float& rz) {
  float nv2 = qx * qx + qy * qy + qz * qz;
  float nv  = nv2 * fast_rsq(fmaxf(nv2, 1e-20f));   // sqrt(nv2), safe at 0
  float wc  = fminf(fmaxf(qw, -0.999999f), 0.999999f);
  float ang = 2.0f * atan2_pos(nv, wc);
  float k   = ang * fast_rcp(nv + 1e-6f);
  k = (nv < 1e-6f) ? 2.0f : k;
  rx = k * qx; ry = k * qy; rz = k * qz;
}

__device__ __forceinline__ void normalize4_fast(float& x, float& y, float& z, float& w) {
  float inv = fast_rsq(x * x + y * y + z * z + w * w);
  x *= inv; y *= inv; z *= inv; w *= inv;
}

// dyn core with pre-clamped physical T/tau; constant divides folded to muls.
__device__ __forceinline__ void dyn_core(
    float qx, float qy, float qz, float qw,
    float wx, float wy, float wz,
    float T, float tqx, float tqy, float tqz,
    float& ax, float& ay, float& az,
    float& qdx, float& qdy, float& qdz, float& qdw,
    float& wdx, float& wdy, float& wdz) {
  // thrust_w = quat_rotate(q, (0,0,T)); t = 2*cross(qv,(0,0,T)) = (2qyT, -2qxT, 0)
  float tx = 2.0f * (qy * T);
  float ty = -2.0f * (qx * T);
  float cx = -qz * ty;
  float cy =  qz * tx;
  float cz = qx * ty - qy * tx;
  ax = (qw * tx + cx) * kInvM;
  ay = (qw * ty + cy) * kInvM;
  az = (T + cz - kMG) * kInvM;

  // omega_dot = J^-1 (tau - omega x (J omega)); J diagonal
  float Jwx = kJx * wx, Jwy = kJy * wy, Jwz = kJz * wz;
  wdx = (tqx - (wy * Jwz - wz * Jwy)) * kInvJx;
  wdy = (tqy - (wz * Jwx - wx * Jwz)) * kInvJy;
  wdz = (tqz - (wx * Jwy - wy * Jwx)) * kInvJz;

  // quat derivative
  qdx = 0.5f * (qw * wx + (qy * wz - qz * wy));
  qdy = 0.5f * (qw * wy + (qz * wx - qx * wz));
  qdz = 0.5f * (qw * wz + (qx * wy - qy * wx));
  qdw = -0.5f * (qx * wx + qy * wy + qz * wz);
}

__global__ __launch_bounds__(64) void quad_rk4_kernel(
    const float* __restrict__ x0,
    const float* __restrict__ u_seq,
    float* __restrict__ out) {
  const int b = blockIdx.x * 64 + threadIdx.x;
  if (b >= kB) return;

  const float4* xv = reinterpret_cast<const float4*>(x0) + (size_t)b * 3;
  float4 s0 = xv[0], s1 = xv[1], s2 = xv[2];
  float px = s0.x, py = s0.y, pz = s0.z;
  float vx = s0.w, vy = s1.x, vz = s1.y;
  float ox = s2.y, oy = s2.z, oz = s2.w;

  float qx, qy, qz, qw;                       // loop-carried unit quaternion
  so3_to_quat_init(s1.z, s1.w, s2.x, qx, qy, qz, qw);

  const float4* uv = reinterpret_cast<const float4*>(u_seq) + (size_t)b * kN;
  f32x4*        ov = reinterpret_cast<f32x4*>(out) + (size_t)b * kN * 3;

  // depth-8 software-prefetch pipeline: 8 loads in flight, each issued
  // 8 full step-bodies (~8000 cyc) before its use.
  float4 u0 = uv[0], u1 = uv[1], u2 = uv[2], u3 = uv[3],
         u4 = uv[4], u5 = uv[5], u6 = uv[6], u7 = uv[7];

#pragma unroll 8
  for (int t = 0; t < kN; ++t) {
    // issue load for t+kPF now; consumed 8 iterations later
    float4 u_new = uv[(t + kPF < kN) ? (t + kPF) : (kN - 1)];
    float4 u = u0;

    // motor_to_phys folded with dyn's clip*scale: T=min(KT*s,Tmax), tau=clamp(raw,±MT)
    float w20 = u.x * u.x, w21 = u.y * u.y, w22 = u.z * u.z, w23 = u.w * u.w;
    float T   = fminf(kKT * (w20 + w21 + w22 + w23), kTmax);   // >=0 always
    float tq1 = kKT * kArm * ((w22 + w23) - (w20 + w21));
    float tq2 = kKT * kArm * ((w21 + w22) - (w20 + w23));
    float tq3 = kKC * ((w20 + w22) - (w21 + w23));
    tq1 = fminf(fmaxf(tq1, -kTq0), kTq0);
    tq2 = fminf(fmaxf(tq2, -kTq1), kTq1);
    tq3 = fminf(fmaxf(tq3, -kTq2), kTq2);

    // ---- stage 1 ----
    float a1x, a1y, a1z, qd1x, qd1y, qd1z, qd1w, wd1x, wd1y, wd1z;
    dyn_core(qx, qy, qz, qw, ox, oy, oz, T, tq1, tq2, tq3,
             a1x, a1y, a1z, qd1x, qd1y, qd1z, qd1w, wd1x, wd1y, wd1z);

    // ---- stage 2 ----
    float v2x = vx + kH * a1x, v2y = vy + kH * a1y, v2z = vz + kH * a1z;
    float o2x = ox + kH * wd1x, o2y = oy + kH * wd1y, o2z = oz + kH * wd1z;
    float q2x = qx + kH * qd1x, q2y = qy + kH * qd1y,
          q2z = qz + kH * qd1z, q2w = qw + kH * qd1w;
    normalize4_fast(q2x, q2y, q2z, q2w);
    float a2x, a2y, a2z, qd2x, qd2y, qd2z, qd2w, wd2x, wd2y, wd2z;
    dyn_core(q2x, q2y, q2z, q2w, o2x, o2y, o2z, T, tq1, tq2, tq3,
             a2x, a2y, a2z, qd2x, qd2y, qd2z, qd2w, wd2x, wd2y, wd2z);

    // ---- stage 3 ----
    float v3x = vx + kH * a2x, v3y = vy + kH * a2y, v3z = vz + kH * a2z;
    float o3x = ox + kH * wd2x, o3y = oy + kH * wd2y, o3z = oz + kH * wd2z;
    float q3x = qx + kH * qd2x, q3y = qy + kH * qd2y,
          q3z = qz + kH * qd2z, q3w = qw + kH * qd2w;
    normalize4_fast(q3x, q3y, q3z, q3w);
    float a3x, a3y, a3z, qd3x, qd3y, qd3z, qd3w, wd3x, wd3y, wd3z;
    dyn_core(q3x, q3y, q3z, q3w, o3x, o3y, o3z, T, tq1, tq2, tq3,
             a3x, a3y, a3z, qd3x, qd3y, qd3z, qd3w, wd3x, wd3y, wd3z);

    // ---- stage 4 (full step) ----
    float v4x = vx + kDT * a3x, v4y = vy + kDT * a3y, v4z = vz + kDT * a3z;
    float o4x = ox + kDT * wd3x, o4y = oy + kDT * wd3y, o4z = oz + kDT * wd3z;
    float q4x = qx + kDT * qd3x, q4y = qy + kDT * qd3y,
          q4z = qz + kDT * qd3z, q4w = qw + kDT * qd3w;
    normalize4_fast(q4x, q4y, q4z, q4w);
    float a4x, a4y, a4z, qd4x, qd4y, qd4z, qd4w, wd4x, wd4y, wd4z;
    dyn_core(q4x, q4y, q4z, q4w, o4x, o4y, o4z, T, tq1, tq2, tq3,
             a4x, a4y, a4z, qd4x, qd4y, qd4z, qd4w, wd4x, wd4y, wd4z);

    // ---- RK4 combine (pos uses v1 = old vel; update pos BEFORE vel) ----
    px += kDT6 * (vx + 2.0f * v2x + 2.0f * v3x + v4x);
    py += kDT6 * (vy + 2.0f * v2y + 2.0f * v3y + v4y);
    pz += kDT6 * (vz + 2.0f * v2z + 2.0f * v3z + v4z);
    vx += kDT6 * (a1x + 2.0f * a2x + 2.0f * a3x + a4x);
    vy += kDT6 * (a1y + 2.0f * a2y + 2.0f * a3y + a4y);
    vz += kDT6 * (a1z + 2.0f * a2z + 2.0f * a3z + a4z);
    ox += kDT6 * (wd1x + 2.0f * wd2x + 2.0f * wd3x + wd4x);
    oy += kDT6 * (wd1y + 2.0f * wd2y + 2.0f * wd3y + wd4y);
    oz += kDT6 * (wd1z + 2.0f * wd2z + 2.0f * wd3z + wd4z);
    qx += kDT6 * (qd1x + 2.0f * qd2x + 2.0f * qd3x + qd4x);
    qy += kDT6 * (qd1y + 2.0f * qd2y + 2.0f * qd3y + qd4y);
    qz += kDT6 * (qd1z + 2.0f * qd2z + 2.0f * qd3z + qd4z);
    qw += kDT6 * (qd1w + 2.0f * qd2w + 2.0f * qd3w + qd4w);
    normalize4_fast(qx, qy, qz, qw);

    // output so3 (not fed back — poly atan2 error does not compound)
    float rx, ry, rz;
    quat_to_so3_fast(qx, qy, qz, qw, rx, ry, rz);

    // write-once output: nontemporal to skip L2 write-allocate
    f32x4 o0 = {px, py, pz, vx};
    f32x4 o1 = {vy, vz, rx, ry};
    f32x4 o2 = {rz, ox, oy, oz};
    __builtin_nontemporal_store(o0, &ov[t * 3 + 0]);
    __builtin_nontemporal_store(o1, &ov[t * 3 + 1]);
    __builtin_nontemporal_store(o2, &ov[t * 3 + 2]);

    // rotate the 8-deep prefetch pipeline (free renames after unroll-8)
    u0 = u1; u1 = u2; u2 = u3; u3 = u4; u4 = u5; u5 = u6; u6 = u7; u7 = u_new;
  }
}

extern "C" void kernel_launch(void* const* d_in, const int* in_sizes, int n_in,
                              void* d_out, int out_size, void* d_ws, size_t ws_size,
                              hipStream_t stream) {
  const float* x0    = (const float*)d_in[0];   // (8192, 12)
  const float* u_seq = (const float*)d_in[1];   // (8192, 256, 4)
  float*       out   = (float*)d_out;           // (8192, 256, 12)
  (void)in_sizes; (void)n_in; (void)out_size; (void)d_ws; (void)ws_size;

  dim3 block(64);
  dim3 grid(kB / 64);   // 128 waves, 1 thread per trajectory
  quad_rk4_kernel<<<grid, block, 0, stream>>>(x0, u_seq, out);
}

// Round 6
// 287.185 us; speedup vs baseline: 1.1280x; 1.1280x over previous
//
#include <hip/hip_runtime.h>
#include <math.h>

// PhysQuadModel: batched RK4 rollout of quadrotor dynamics.
// One thread per trajectory (B=8192), 256 sequential RK4 steps.
// R2: quaternion carried as loop state (exp(log(q))==q), poly atan2 for the
//     output-only log map, reciprocal-multiplies, v_rsq normalize.
// R3: distance-2 u prefetch (268->227us rocprof).
// R4/R5: NT stores REGRESSED (WRITE_SIZE 99.5->362 MB, 3.6x write
//     amplification: per-trajectory-contiguous layout means a wave's NT
//     stores hit 192 distinct 64B lines/step; normal stores let L2 merge).
// R6: normal float4 stores + keep depth-8 u prefetch (isolates prefetch
//     depth vs R3's distance-2).

namespace {
constexpr int   kB    = 8192;
constexpr int   kN    = 256;
constexpr float kDT   = 0.01f;
constexpr float kMG   = 0.033f * 9.81f;        // M*G
constexpr float kTmax = 1.9f * 0.033f * 9.81f; // 0.6150870
constexpr float kKT   = 3.8e-08f;
constexpr float kKC   = 3.8e-11f;
constexpr float kArm  = 0.04f;
constexpr float kInvM = 1.0f / 0.033f;
constexpr float kJx   = 1.4e-05f, kJy = 1.4e-05f, kJz = 2.17e-05f;
constexpr float kInvJx = 1.0f / 1.4e-05f, kInvJy = 1.0f / 1.4e-05f,
                kInvJz = 1.0f / 2.17e-05f;
constexpr float kTq0  = 0.009f, kTq1 = 0.009f, kTq2 = 0.002f;
constexpr float kH    = 0.005f;                // 0.5*dt
constexpr float kDT6  = 0.0016666667f;         // dt/6
constexpr int   kPF   = 8;                     // prefetch pipeline depth
}

__device__ __forceinline__ float fast_rcp(float x) { return __builtin_amdgcn_rcpf(x); }
__device__ __forceinline__ float fast_rsq(float x) { return __builtin_amdgcn_rsqf(x); }

// atan2 for y >= 0, result in [0, pi]. Minimax atan poly on [0,1], err ~1e-5.
__device__ __forceinline__ float atan2_pos(float y, float x) {
  float axx = fabsf(x);
  float mn  = fminf(y, axx);
  float mx  = fmaxf(y, axx);
  float t   = mn * fast_rcp(mx);
  float t2  = t * t;
  float p = fmaf(t2, -0.01172120f, 0.05265332f);
  p = fmaf(t2, p, -0.11643287f);
  p = fmaf(t2, p, 0.19354346f);
  p = fmaf(t2, p, -0.33262347f);
  p = fmaf(t2, p, 0.99997726f);
  p *= t;
  p = (y > axx) ? (1.5707963268f - p) : p;
  p = (x < 0.0f) ? (3.1415926536f - p) : p;
  return p;
}

// accurate version used ONCE at init (outside the hot loop)
__device__ __forceinline__ void so3_to_quat_init(float rx, float ry, float rz,
                                                 float& qx, float& qy, float& qz, float& qw) {
  float theta = sqrtf(rx * rx + ry * ry + rz * rz);
  float half  = 0.5f * theta;
  float s     = sinf(half);
  float c     = cosf(half);
  float k     = s / (theta + 1e-8f);
  bool  small = theta < 1e-6f;
  k  = small ? 0.5f : k;
  qw = small ? 1.0f : c;
  qx = k * rx; qy = k * ry; qz = k * rz;
}

// log map, output-only path (not fed back into state)
__device__ __forceinline__ void quat_to_so3_fast(float qx, float qy, float qz, float qw,
                                                 float& rx, float& ry, float& rz) {
  float nv2 = qx * qx + qy * qy + qz * qz;
  float nv  = nv2 * fast_rsq(fmaxf(nv2, 1e-20f));   // sqrt(nv2), safe at 0
  float wc  = fminf(fmaxf(qw, -0.999999f), 0.999999f);
  float ang = 2.0f * atan2_pos(nv, wc);
  float k   = ang * fast_rcp(nv + 1e-6f);
  k = (nv < 1e-6f) ? 2.0f : k;
  rx = k * qx; ry = k * qy; rz = k * qz;
}

__device__ __forceinline__ void normalize4_fast(float& x, float& y, float& z, float& w) {
  float inv = fast_rsq(x * x + y * y + z * z + w * w);
  x *= inv; y *= inv; z *= inv; w *= inv;
}

// dyn core with pre-clamped physical T/tau; constant divides folded to muls.
__device__ __forceinline__ void dyn_core(
    float qx, float qy, float qz, float qw,
    float wx, float wy, float wz,
    float T, float tqx, float tqy, float tqz,
    float& ax, float& ay, float& az,
    float& qdx, float& qdy, float& qdz, float& qdw,
    float& wdx, float& wdy, float& wdz) {
  // thrust_w = quat_rotate(q, (0,0,T)); t = 2*cross(qv,(0,0,T)) = (2qyT, -2qxT, 0)
  float tx = 2.0f * (qy * T);
  float ty = -2.0f * (qx * T);
  float cx = -qz * ty;
  float cy =  qz * tx;
  float cz = qx * ty - qy * tx;
  ax = (qw * tx + cx) * kInvM;
  ay = (qw * ty + cy) * kInvM;
  az = (T + cz - kMG) * kInvM;

  // omega_dot = J^-1 (tau - omega x (J omega)); J diagonal
  float Jwx = kJx * wx, Jwy = kJy * wy, Jwz = kJz * wz;
  wdx = (tqx - (wy * Jwz - wz * Jwy)) * kInvJx;
  wdy = (tqy - (wz * Jwx - wx * Jwz)) * kInvJy;
  wdz = (tqz - (wx * Jwy - wy * Jwx)) * kInvJz;

  // quat derivative
  qdx = 0.5f * (qw * wx + (qy * wz - qz * wy));
  qdy = 0.5f * (qw * wy + (qz * wx - qx * wz));
  qdz = 0.5f * (qw * wz + (qx * wy - qy * wx));
  qdw = -0.5f * (qx * wx + qy * wy + qz * wz);
}

__global__ __launch_bounds__(64) void quad_rk4_kernel(
    const float* __restrict__ x0,
    const float* __restrict__ u_seq,
    float* __restrict__ out) {
  const int b = blockIdx.x * 64 + threadIdx.x;
  if (b >= kB) return;

  const float4* xv = reinterpret_cast<const float4*>(x0) + (size_t)b * 3;
  float4 s0 = xv[0], s1 = xv[1], s2 = xv[2];
  float px = s0.x, py = s0.y, pz = s0.z;
  float vx = s0.w, vy = s1.x, vz = s1.y;
  float ox = s2.y, oy = s2.z, oz = s2.w;

  float qx, qy, qz, qw;                       // loop-carried unit quaternion
  so3_to_quat_init(s1.z, s1.w, s2.x, qx, qy, qz, qw);

  const float4* uv = reinterpret_cast<const float4*>(u_seq) + (size_t)b * kN;
  float4*       ov = reinterpret_cast<float4*>(out) + (size_t)b * kN * 3;

  // depth-8 software-prefetch pipeline: 8 loads in flight, each issued
  // 8 full step-bodies (~8000 cyc) before its use.
  float4 u0 = uv[0], u1 = uv[1], u2 = uv[2], u3 = uv[3],
         u4 = uv[4], u5 = uv[5], u6 = uv[6], u7 = uv[7];

#pragma unroll 8
  for (int t = 0; t < kN; ++t) {
    // issue load for t+kPF now; consumed 8 iterations later
    float4 u_new = uv[(t + kPF < kN) ? (t + kPF) : (kN - 1)];
    float4 u = u0;

    // motor_to_phys folded with dyn's clip*scale: T=min(KT*s,Tmax), tau=clamp(raw,±MT)
    float w20 = u.x * u.x, w21 = u.y * u.y, w22 = u.z * u.z, w23 = u.w * u.w;
    float T   = fminf(kKT * (w20 + w21 + w22 + w23), kTmax);   // >=0 always
    float tq1 = kKT * kArm * ((w22 + w23) - (w20 + w21));
    float tq2 = kKT * kArm * ((w21 + w22) - (w20 + w23));
    float tq3 = kKC * ((w20 + w22) - (w21 + w23));
    tq1 = fminf(fmaxf(tq1, -kTq0), kTq0);
    tq2 = fminf(fmaxf(tq2, -kTq1), kTq1);
    tq3 = fminf(fmaxf(tq3, -kTq2), kTq2);

    // ---- stage 1 ----
    float a1x, a1y, a1z, qd1x, qd1y, qd1z, qd1w, wd1x, wd1y, wd1z;
    dyn_core(qx, qy, qz, qw, ox, oy, oz, T, tq1, tq2, tq3,
             a1x, a1y, a1z, qd1x, qd1y, qd1z, qd1w, wd1x, wd1y, wd1z);

    // ---- stage 2 ----
    float v2x = vx + kH * a1x, v2y = vy + kH * a1y, v2z = vz + kH * a1z;
    float o2x = ox + kH * wd1x, o2y = oy + kH * wd1y, o2z = oz + kH * wd1z;
    float q2x = qx + kH * qd1x, q2y = qy + kH * qd1y,
          q2z = qz + kH * qd1z, q2w = qw + kH * qd1w;
    normalize4_fast(q2x, q2y, q2z, q2w);
    float a2x, a2y, a2z, qd2x, qd2y, qd2z, qd2w, wd2x, wd2y, wd2z;
    dyn_core(q2x, q2y, q2z, q2w, o2x, o2y, o2z, T, tq1, tq2, tq3,
             a2x, a2y, a2z, qd2x, qd2y, qd2z, qd2w, wd2x, wd2y, wd2z);

    // ---- stage 3 ----
    float v3x = vx + kH * a2x, v3y = vy + kH * a2y, v3z = vz + kH * a2z;
    float o3x = ox + kH * wd2x, o3y = oy + kH * wd2y, o3z = oz + kH * wd2z;
    float q3x = qx + kH * qd2x, q3y = qy + kH * qd2y,
          q3z = qz + kH * qd2z, q3w = qw + kH * qd2w;
    normalize4_fast(q3x, q3y, q3z, q3w);
    float a3x, a3y, a3z, qd3x, qd3y, qd3z, qd3w, wd3x, wd3y, wd3z;
    dyn_core(q3x, q3y, q3z, q3w, o3x, o3y, o3z, T, tq1, tq2, tq3,
             a3x, a3y, a3z, qd3x, qd3y, qd3z, qd3w, wd3x, wd3y, wd3z);

    // ---- stage 4 (full step) ----
    float v4x = vx + kDT * a3x, v4y = vy + kDT * a3y, v4z = vz + kDT * a3z;
    float o4x = ox + kDT * wd3x, o4y = oy + kDT * wd3y, o4z = oz + kDT * wd3z;
    float q4x = qx + kDT * qd3x, q4y = qy + kDT * qd3y,
          q4z = qz + kDT * qd3z, q4w = qw + kDT * qd3w;
    normalize4_fast(q4x, q4y, q4z, q4w);
    float a4x, a4y, a4z, qd4x, qd4y, qd4z, qd4w, wd4x, wd4y, wd4z;
    dyn_core(q4x, q4y, q4z, q4w, o4x, o4y, o4z, T, tq1, tq2, tq3,
             a4x, a4y, a4z, qd4x, qd4y, qd4z, qd4w, wd4x, wd4y, wd4z);

    // ---- RK4 combine (pos uses v1 = old vel; update pos BEFORE vel) ----
    px += kDT6 * (vx + 2.0f * v2x + 2.0f * v3x + v4x);
    py += kDT6 * (vy + 2.0f * v2y + 2.0f * v3y + v4y);
    pz += kDT6 * (vz + 2.0f * v2z + 2.0f * v3z + v4z);
    vx += kDT6 * (a1x + 2.0f * a2x + 2.0f * a3x + a4x);
    vy += kDT6 * (a1y + 2.0f * a2y + 2.0f * a3y + a4y);
    vz += kDT6 * (a1z + 2.0f * a2z + 2.0f * a3z + a4z);
    ox += kDT6 * (wd1x + 2.0f * wd2x + 2.0f * wd3x + wd4x);
    oy += kDT6 * (wd1y + 2.0f * wd2y + 2.0f * wd3y + wd4y);
    oz += kDT6 * (wd1z + 2.0f * wd2z + 2.0f * wd3z + wd4z);
    qx += kDT6 * (qd1x + 2.0f * qd2x + 2.0f * qd3x + qd4x);
    qy += kDT6 * (qd1y + 2.0f * qd2y + 2.0f * qd3y + qd4y);
    qz += kDT6 * (qd1z + 2.0f * qd2z + 2.0f * qd3z + qd4z);
    qw += kDT6 * (qd1w + 2.0f * qd2w + 2.0f * qd3w + qd4w);
    normalize4_fast(qx, qy, qz, qw);

    // output so3 (not fed back — poly atan2 error does not compound)
    float rx, ry, rz;
    quat_to_so3_fast(qx, qy, qz, qw, rx, ry, rz);

    // normal stores: L2 merges each thread's 48 B/step into full lines
    ov[t * 3 + 0] = make_float4(px, py, pz, vx);
    ov[t * 3 + 1] = make_float4(vy, vz, rx, ry);
    ov[t * 3 + 2] = make_float4(rz, ox, oy, oz);

    // rotate the 8-deep prefetch pipeline (free renames after unroll-8)
    u0 = u1; u1 = u2; u2 = u3; u3 = u4; u4 = u5; u5 = u6; u6 = u7; u7 = u_new;
  }
}

extern "C" void kernel_launch(void* const* d_in, const int* in_sizes, int n_in,
                              void* d_out, int out_size, void* d_ws, size_t ws_size,
                              hipStream_t stream) {
  const float* x0    = (const float*)d_in[0];   // (8192, 12)
  const float* u_seq = (const float*)d_in[1];   // (8192, 256, 4)
  float*       out   = (float*)d_out;           // (8192, 256, 12)
  (void)in_sizes; (void)n_in; (void)out_size; (void)d_ws; (void)ws_size;

  dim3 block(64);
  dim3 grid(kB / 64);   // 128 waves, 1 thread per trajectory
  quad_rk4_kernel<<<grid, block, 0, stream>>>(x0, u_seq, out);
}